// Round 1
// baseline (6824.255 us; speedup 1.0000x reference)
//
#include <hip/hip_runtime.h>
#include <math.h>

#define B_   512
#define L_   128
#define K_   9
#define NE   50000
#define ZD   16
#define TE   32
#define XE   128
#define EP   8
#define H_   128
#define G4   512
#define OD   32
#define IN0  184
#define MKD  168
#define RB   4

__device__ __forceinline__ float sigm(float x) {
    x = fminf(fmaxf(x, -30.f), 30.f);
    return 1.f / (1.f + expf(-x));
}
__device__ __forceinline__ float tanh_f(float x) {
    x = fminf(fmaxf(x, -15.f), 15.f);
    float e = expf(2.f * x);
    return (e - 1.f) / (e + 1.f);
}

// ---------------------------------------------------------------------------
// Kernel A: pred_t + mkx precompute.  One thread per (b,l,k) item.
// Weights indexed wave-uniformly -> scalar loads; per-lane gathers in VGPRs.
// ---------------------------------------------------------------------------
extern "C" __global__ void __launch_bounds__(256)
kA(const int* __restrict__ x, const int* __restrict__ dpt, const int* __restrict__ adj,
   const float* __restrict__ eprop, const float* __restrict__ x_emb,
   const float* __restrict__ t_emb, const float* __restrict__ tcost,
   const float* __restrict__ wat, const float* __restrict__ bat,
   const float* __restrict__ wmx, const float* __restrict__ bmx,
   const float* __restrict__ wmt, const float* __restrict__ bmt,
   float* __restrict__ mkx_ws, float* __restrict__ pred_t)
{
    int gid = blockIdx.x * 256 + threadIdx.x;
    if (gid >= B_ * L_ * K_) return;
    int k  = gid % K_;
    int bl = gid / K_;
    int xt = x[bl];
    int dt = dpt[bl];
    int a  = adj[xt * K_ + k];

    float accx[OD], acct[OD];
#pragma unroll
    for (int o = 0; o < OD; ++o) { accx[o] = 0.f; acct[o] = 0.f; }

    // section 1: x_emb[a], cols 0..127
    for (int d = 0; d < XE; d += 4) {
        float4 m4 = *(const float4*)(x_emb + (size_t)a * XE + d);
        float mv[4] = {m4.x, m4.y, m4.z, m4.w};
#pragma unroll
        for (int q = 0; q < 4; ++q)
#pragma unroll
            for (int o = 0; o < OD; ++o) {
                accx[o] = fmaf(mv[q], wmx[o * MKD + d + q], accx[o]);
                acct[o] = fmaf(mv[q], wmt[o * MKD + d + q], acct[o]);
            }
    }
    // section 2: t_emb[dt], cols 128..159
    for (int d = 0; d < TE; d += 4) {
        float4 m4 = *(const float4*)(t_emb + (size_t)dt * TE + d);
        float mv[4] = {m4.x, m4.y, m4.z, m4.w};
#pragma unroll
        for (int q = 0; q < 4; ++q)
#pragma unroll
            for (int o = 0; o < OD; ++o) {
                accx[o] = fmaf(mv[q], wmx[o * MKD + XE + d + q], accx[o]);
                acct[o] = fmaf(mv[q], wmt[o * MKD + XE + d + q], acct[o]);
            }
    }
    // section 3: eprop[a], cols 160..167
    {
        float4 m4a = *(const float4*)(eprop + (size_t)a * EP);
        float4 m4b = *(const float4*)(eprop + (size_t)a * EP + 4);
        float mv[8] = {m4a.x, m4a.y, m4a.z, m4a.w, m4b.x, m4b.y, m4b.z, m4b.w};
#pragma unroll
        for (int q = 0; q < 8; ++q)
#pragma unroll
            for (int o = 0; o < OD; ++o) {
                accx[o] = fmaf(mv[q], wmx[o * MKD + XE + TE + q], accx[o]);
                acct[o] = fmaf(mv[q], wmt[o * MKD + XE + TE + q], acct[o]);
            }
    }

    // write mkx (+bmx)
    float* mout = mkx_ws + (size_t)gid * OD;
#pragma unroll
    for (int o = 0; o < OD; ++o) mout[o] = accx[o] + bmx[o];

    // aftert pass: concat[tcost_emb[a](32) | tt(32)] @ wat.T
    float acca[OD];
#pragma unroll
    for (int o = 0; o < OD; ++o) acca[o] = 0.f;
    for (int d = 0; d < TE; d += 4) {
        float4 m4 = *(const float4*)(tcost + (size_t)a * TE + d);
        float mv[4] = {m4.x, m4.y, m4.z, m4.w};
#pragma unroll
        for (int q = 0; q < 4; ++q)
#pragma unroll
            for (int o = 0; o < OD; ++o)
                acca[o] = fmaf(mv[q], wat[o * 64 + d + q], acca[o]);
    }
    for (int d = 0; d < TE; d += 4) {
        float4 m4 = *(const float4*)(t_emb + (size_t)dt * TE + d);
        float mv[4] = {m4.x, m4.y, m4.z, m4.w};
#pragma unroll
        for (int q = 0; q < 4; ++q)
#pragma unroll
            for (int o = 0; o < OD; ++o)
                acca[o] = fmaf(mv[q], wat[o * 64 + TE + d + q], acca[o]);
    }

    float pt = 0.f;
#pragma unroll
    for (int o = 0; o < OD; ++o) {
        float at = acca[o] + bat[o];
        at = at > 0.f ? at : 0.f;
        float mt = acct[o] + bmt[o];
        pt = fmaf(at, mt, pt);
    }
    pred_t[gid] = 1.f / (1.f + expf(-pt));
}

// ---------------------------------------------------------------------------
// Kernel P0: g0[bl][512] = hid @ w_ih0.T + b_ih0 + b_hh0.
// Wave-uniform output chunk (64 gates) -> scalar weight loads.
// ---------------------------------------------------------------------------
extern "C" __global__ void __launch_bounds__(256)
kP0(const int* __restrict__ x, const int* __restrict__ dpt,
    const float* __restrict__ z, const float* __restrict__ eprop,
    const float* __restrict__ x_emb, const float* __restrict__ t_emb,
    const float* __restrict__ w_ih0, const float* __restrict__ b_ih0,
    const float* __restrict__ b_hh0, float* __restrict__ g0)
{
    int wid   = (blockIdx.x * 256 + threadIdx.x) >> 6;
    int lane  = threadIdx.x & 63;
    int chunk = wid & 7;          // wave-uniform: which 64-gate chunk
    int grp   = wid >> 3;
    int bl    = grp * 64 + lane;  // 0..65535
    int b     = bl >> 7;
    int l     = bl & 127;
    int xt = x[bl];
    int dt = dpt[bl];

    float acc[64];
#pragma unroll
    for (int j = 0; j < 64; ++j) acc[j] = 0.f;
    const float* wbase = w_ih0 + (size_t)(chunk * 64) * IN0;

    // z cols 0..15
    for (int d = 0; d < ZD; d += 4) {
        float4 m4 = *(const float4*)(z + ((size_t)l * B_ + b) * ZD + d);
        float mv[4] = {m4.x, m4.y, m4.z, m4.w};
#pragma unroll
        for (int q = 0; q < 4; ++q)
#pragma unroll
            for (int j = 0; j < 64; ++j)
                acc[j] = fmaf(mv[q], wbase[j * IN0 + d + q], acc[j]);
    }
    // x_emb cols 16..143
    for (int d = 0; d < XE; d += 4) {
        float4 m4 = *(const float4*)(x_emb + (size_t)xt * XE + d);
        float mv[4] = {m4.x, m4.y, m4.z, m4.w};
#pragma unroll
        for (int q = 0; q < 4; ++q)
#pragma unroll
            for (int j = 0; j < 64; ++j)
                acc[j] = fmaf(mv[q], wbase[j * IN0 + ZD + d + q], acc[j]);
    }
    // t_emb cols 144..175
    for (int d = 0; d < TE; d += 4) {
        float4 m4 = *(const float4*)(t_emb + (size_t)dt * TE + d);
        float mv[4] = {m4.x, m4.y, m4.z, m4.w};
#pragma unroll
        for (int q = 0; q < 4; ++q)
#pragma unroll
            for (int j = 0; j < 64; ++j)
                acc[j] = fmaf(mv[q], wbase[j * IN0 + ZD + XE + d + q], acc[j]);
    }
    // eprop cols 176..183
    {
        float4 m4a = *(const float4*)(eprop + (size_t)xt * EP);
        float4 m4b = *(const float4*)(eprop + (size_t)xt * EP + 4);
        float mv[8] = {m4a.x, m4a.y, m4a.z, m4a.w, m4b.x, m4b.y, m4b.z, m4b.w};
#pragma unroll
        for (int q = 0; q < 8; ++q)
#pragma unroll
            for (int j = 0; j < 64; ++j)
                acc[j] = fmaf(mv[q], wbase[j * IN0 + ZD + XE + TE + q], acc[j]);
    }

    float* gout = g0 + (size_t)bl * G4 + chunk * 64;
#pragma unroll
    for (int j = 0; j < 64; ++j)
        gout[j] = acc[j] + b_ih0[chunk * 64 + j] + b_hh0[chunk * 64 + j];
}

// ---------------------------------------------------------------------------
// Kernel S: the sequential 3-layer LSTM.  128 blocks x 512 threads; each block
// owns RB=4 batch rows for all 128 steps; h/c live in LDS; one gate per thread.
// ---------------------------------------------------------------------------
extern "C" __global__ void __launch_bounds__(512)
kS(const float* __restrict__ g0,
   const float* __restrict__ w_hh0,
   const float* __restrict__ w_ih1, const float* __restrict__ w_hh1,
   const float* __restrict__ b_ih1, const float* __restrict__ b_hh1,
   const float* __restrict__ w_ih2, const float* __restrict__ w_hh2,
   const float* __restrict__ b_ih2, const float* __restrict__ b_hh2,
   float* __restrict__ h2s)
{
    __shared__ float sh0[RB][H_], sc0[RB][H_];
    __shared__ float sh1[RB][H_], sc1[RB][H_];
    __shared__ float sh2[RB][H_], sc2[RB][H_];
    __shared__ float sg[RB][G4];

    const int t  = threadIdx.x;       // 0..511 : one gate output per thread
    const int b0 = blockIdx.x * RB;

    ((float*)sh0)[t] = 0.f; ((float*)sc0)[t] = 0.f;
    ((float*)sh1)[t] = 0.f; ((float*)sc1)[t] = 0.f;
    ((float*)sh2)[t] = 0.f; ((float*)sc2)[t] = 0.f;
    __syncthreads();

    const float bL1 = b_ih1[t] + b_hh1[t];
    const float bL2 = b_ih2[t] + b_hh2[t];
    const float* wh0p = w_hh0 + (size_t)t * H_;
    const float* wi1p = w_ih1 + (size_t)t * H_;
    const float* wh1p = w_hh1 + (size_t)t * H_;
    const float* wi2p = w_ih2 + (size_t)t * H_;
    const float* wh2p = w_hh2 + (size_t)t * H_;
    const int r_  = t >> 7;
    const int hd_ = t & (H_ - 1);

    for (int l = 0; l < L_; ++l) {
        // ---- layer 0 gates: g0 (precomputed input part) + h0 @ w_hh0.T ----
        {
            float acc[RB];
#pragma unroll
            for (int r = 0; r < RB; ++r)
                acc[r] = g0[((size_t)(b0 + r) * L_ + l) * G4 + t];
            for (int d = 0; d < H_; d += 4) {
                float4 w = *(const float4*)(wh0p + d);
#pragma unroll
                for (int r = 0; r < RB; ++r) {
                    float4 hv = *(const float4*)&sh0[r][d];
                    acc[r] += w.x * hv.x + w.y * hv.y + w.z * hv.z + w.w * hv.w;
                }
            }
#pragma unroll
            for (int r = 0; r < RB; ++r) sg[r][t] = acc[r];
        }
        __syncthreads();
        // ---- layer 0 cell update ----
        {
            float gi = sg[r_][hd_], gf = sg[r_][H_ + hd_];
            float gg = sg[r_][2 * H_ + hd_], go = sg[r_][3 * H_ + hd_];
            float c = sigm(gf) * sc0[r_][hd_] + sigm(gi) * tanh_f(gg);
            float h = sigm(go) * tanh_f(c);
            sc0[r_][hd_] = c; sh0[r_][hd_] = h;
        }
        __syncthreads();
        // ---- layer 1 gates ----
        {
            float acc[RB];
#pragma unroll
            for (int r = 0; r < RB; ++r) acc[r] = bL1;
            for (int d = 0; d < H_; d += 4) {
                float4 wi = *(const float4*)(wi1p + d);
                float4 wh = *(const float4*)(wh1p + d);
#pragma unroll
                for (int r = 0; r < RB; ++r) {
                    float4 h0v = *(const float4*)&sh0[r][d];
                    float4 h1v = *(const float4*)&sh1[r][d];
                    acc[r] += wi.x * h0v.x + wi.y * h0v.y + wi.z * h0v.z + wi.w * h0v.w
                            + wh.x * h1v.x + wh.y * h1v.y + wh.z * h1v.z + wh.w * h1v.w;
                }
            }
#pragma unroll
            for (int r = 0; r < RB; ++r) sg[r][t] = acc[r];
        }
        __syncthreads();
        // ---- layer 1 cell update ----
        {
            float gi = sg[r_][hd_], gf = sg[r_][H_ + hd_];
            float gg = sg[r_][2 * H_ + hd_], go = sg[r_][3 * H_ + hd_];
            float c = sigm(gf) * sc1[r_][hd_] + sigm(gi) * tanh_f(gg);
            float h = sigm(go) * tanh_f(c);
            sc1[r_][hd_] = c; sh1[r_][hd_] = h;
        }
        __syncthreads();
        // ---- layer 2 gates ----
        {
            float acc[RB];
#pragma unroll
            for (int r = 0; r < RB; ++r) acc[r] = bL2;
            for (int d = 0; d < H_; d += 4) {
                float4 wi = *(const float4*)(wi2p + d);
                float4 wh = *(const float4*)(wh2p + d);
#pragma unroll
                for (int r = 0; r < RB; ++r) {
                    float4 h1v = *(const float4*)&sh1[r][d];
                    float4 h2v = *(const float4*)&sh2[r][d];
                    acc[r] += wi.x * h1v.x + wi.y * h1v.y + wi.z * h1v.z + wi.w * h1v.w
                            + wh.x * h2v.x + wh.y * h2v.y + wh.z * h2v.z + wh.w * h2v.w;
                }
            }
#pragma unroll
            for (int r = 0; r < RB; ++r) sg[r][t] = acc[r];
        }
        __syncthreads();
        // ---- layer 2 cell update + h2 history write ----
        {
            float gi = sg[r_][hd_], gf = sg[r_][H_ + hd_];
            float gg = sg[r_][2 * H_ + hd_], go = sg[r_][3 * H_ + hd_];
            float c = sigm(gf) * sc2[r_][hd_] + sigm(gi) * tanh_f(gg);
            float h = sigm(go) * tanh_f(c);
            sc2[r_][hd_] = c; sh2[r_][hd_] = h;
            h2s[((size_t)(b0 + r_) * L_ + l) * H_ + hd_] = h;
        }
        __syncthreads();
    }
}

// ---------------------------------------------------------------------------
// Kernel X: afterx = relu(h2 @ wax.T + bax); px = afterx . mkx; log_softmax.
// One thread per (b,l).
// ---------------------------------------------------------------------------
extern "C" __global__ void __launch_bounds__(256)
kX(const int* __restrict__ x, const int* __restrict__ adj,
   const float* __restrict__ wax, const float* __restrict__ bax,
   const float* __restrict__ h2s, const float* __restrict__ mkx_ws,
   float* __restrict__ pred_x)
{
    int bl = blockIdx.x * 256 + threadIdx.x;  // 0..65535
    float afterx[OD];
#pragma unroll
    for (int o = 0; o < OD; ++o) afterx[o] = 0.f;

    const float* h2 = h2s + (size_t)bl * H_;
    for (int d = 0; d < H_; d += 4) {
        float4 m4 = *(const float4*)(h2 + d);
        float mv[4] = {m4.x, m4.y, m4.z, m4.w};
#pragma unroll
        for (int q = 0; q < 4; ++q)
#pragma unroll
            for (int o = 0; o < OD; ++o)
                afterx[o] = fmaf(mv[q], wax[o * H_ + d + q], afterx[o]);
    }
#pragma unroll
    for (int o = 0; o < OD; ++o) {
        float v = afterx[o] + bax[o];
        afterx[o] = v > 0.f ? v : 0.f;
    }

    int xt = x[bl];
    float px[K_];
#pragma unroll
    for (int k = 0; k < K_; ++k) {
        const float* mv = mkx_ws + (size_t)bl * (K_ * OD) + k * OD;
        float s = 0.f;
#pragma unroll
        for (int o = 0; o < OD; o += 4) {
            float4 m4 = *(const float4*)(mv + o);
            s += afterx[o] * m4.x + afterx[o + 1] * m4.y
               + afterx[o + 2] * m4.z + afterx[o + 3] * m4.w;
        }
        int a = adj[xt * K_ + k];
        px[k] = (a == NE) ? -INFINITY : s;
    }

    float m = px[0];
#pragma unroll
    for (int k = 1; k < K_; ++k) m = fmaxf(m, px[k]);
    float ssum = 0.f;
#pragma unroll
    for (int k = 0; k < K_; ++k) ssum += expf(px[k] - m);
    float lse = logf(ssum) + m;
#pragma unroll
    for (int k = 0; k < K_; ++k)
        pred_x[(size_t)bl * K_ + k] = px[k] - lse;
}

// ---------------------------------------------------------------------------
extern "C" void kernel_launch(void* const* d_in, const int* in_sizes, int n_in,
                              void* d_out, int out_size, void* d_ws, size_t ws_size,
                              hipStream_t stream)
{
    (void)in_sizes; (void)n_in; (void)out_size; (void)ws_size;

    const int*   x      = (const int*)  d_in[0];
    const int*   dpt    = (const int*)  d_in[1];
    const float* z      = (const float*)d_in[2];
    const int*   adj    = (const int*)  d_in[3];
    const float* eprop  = (const float*)d_in[4];
    const float* x_emb  = (const float*)d_in[5];
    const float* t_emb  = (const float*)d_in[6];
    const float* tcost  = (const float*)d_in[7];
    const float* w_ih0  = (const float*)d_in[8];
    const float* w_hh0  = (const float*)d_in[9];
    const float* b_ih0  = (const float*)d_in[10];
    const float* b_hh0  = (const float*)d_in[11];
    const float* w_ih1  = (const float*)d_in[12];
    const float* w_hh1  = (const float*)d_in[13];
    const float* b_ih1  = (const float*)d_in[14];
    const float* b_hh1  = (const float*)d_in[15];
    const float* w_ih2  = (const float*)d_in[16];
    const float* w_hh2  = (const float*)d_in[17];
    const float* b_ih2  = (const float*)d_in[18];
    const float* b_hh2  = (const float*)d_in[19];
    const float* wax    = (const float*)d_in[20];
    const float* bax    = (const float*)d_in[21];
    const float* wat    = (const float*)d_in[22];
    const float* bat    = (const float*)d_in[23];
    const float* wmx    = (const float*)d_in[24];
    const float* bmx    = (const float*)d_in[25];
    const float* wmt    = (const float*)d_in[26];
    const float* bmt    = (const float*)d_in[27];

    float* out    = (float*)d_out;
    float* pred_x = out;
    float* pred_t = out + (size_t)B_ * L_ * K_;

    float* ws  = (float*)d_ws;
    float* mkx = ws;                                      // B*L*K*32
    float* g0  = mkx + (size_t)B_ * L_ * K_ * OD;         // B*L*512
    float* h2s = g0  + (size_t)B_ * L_ * G4;              // B*L*128

    hipLaunchKernelGGL(kA, dim3((B_ * L_ * K_) / 256), dim3(256), 0, stream,
                       x, dpt, adj, eprop, x_emb, t_emb, tcost,
                       wat, bat, wmx, bmx, wmt, bmt, mkx, pred_t);

    hipLaunchKernelGGL(kP0, dim3((B_ * L_ * 8) / 256), dim3(256), 0, stream,
                       x, dpt, z, eprop, x_emb, t_emb, w_ih0, b_ih0, b_hh0, g0);

    hipLaunchKernelGGL(kS, dim3(B_ / RB), dim3(512), 0, stream,
                       g0, w_hh0, w_ih1, w_hh1, b_ih1, b_hh1,
                       w_ih2, w_hh2, b_ih2, b_hh2, h2s);

    hipLaunchKernelGGL(kX, dim3((B_ * L_) / 256), dim3(256), 0, stream,
                       x, adj, wax, bax, h2s, mkx, pred_x);
}

// Round 2
// 4214.928 us; speedup vs baseline: 1.6191x; 1.6191x over previous
//
#include <hip/hip_runtime.h>
#include <hip/hip_fp16.h>
#include <math.h>
#include <stdint.h>

#define B_   512
#define L_   128
#define K_   9
#define NE   50000
#define ZD   16
#define TE   32
#define XE   128
#define EP   8
#define H_   128
#define G4   512
#define OD   32
#define IN0  184
#define MKD  168
#define RB2  2

typedef uint32_t u32;
typedef _Float16 half2v __attribute__((ext_vector_type(2)));

__device__ __forceinline__ float sigm(float x) {
    x = fminf(fmaxf(x, -30.f), 30.f);
    return 1.f / (1.f + expf(-x));
}
__device__ __forceinline__ float tanh_f(float x) {
    x = fminf(fmaxf(x, -15.f), 15.f);
    float e = expf(2.f * x);
    return (e - 1.f) / (e + 1.f);
}

__device__ __forceinline__ float dot2f(u32 w, u32 h, float acc) {
#if __has_builtin(__builtin_amdgcn_fdot2)
    union { u32 u; half2v v; } a, b;
    a.u = w; b.u = h;
    return __builtin_amdgcn_fdot2(a.v, b.v, acc, false);
#else
    union { u32 u; __half2 h2; } a, b;
    a.u = w; b.u = h;
    float2 fa = __half22float2(a.h2), fb = __half22float2(b.h2);
    return fmaf(fa.x, fb.x, fmaf(fa.y, fb.y, acc));
#endif
}

__device__ __forceinline__ u32 packh(float lo, float hi) {
    union { __half2 h; u32 u; } p;
    p.h = __halves2half2(__float2half(lo), __float2half(hi));
    return p.u;
}

// ---------------------------------------------------------------------------
// kW: pack recurrent weights fp32 -> f16 pairs, layout [j4][gate(512)][4].
// wp0: w_hh0 (16 j4-groups).  wp1: w_ih1 (j4 0..15) | w_hh1 (16..31).
// wp2: w_ih2 | w_hh2.  163840 u32 total.
// ---------------------------------------------------------------------------
extern "C" __global__ void __launch_bounds__(256)
kW(const float* __restrict__ w_hh0,
   const float* __restrict__ w_ih1, const float* __restrict__ w_hh1,
   const float* __restrict__ w_ih2, const float* __restrict__ w_hh2,
   u32* __restrict__ wp0, u32* __restrict__ wp1, u32* __restrict__ wp2)
{
    int gid = blockIdx.x * 256 + threadIdx.x;
    if (gid < 32768) {
        int e = gid;
        int q = e & 3, t = (e >> 2) & 511, j4 = e >> 11;
        int j = j4 * 4 + q;
        wp0[e] = packh(w_hh0[t * H_ + 2 * j], w_hh0[t * H_ + 2 * j + 1]);
    } else if (gid < 98304) {
        int e = gid - 32768;
        int q = e & 3, t = (e >> 2) & 511, j4 = e >> 11;
        const float* m = (j4 < 16) ? w_ih1 : w_hh1;
        int j = (j4 & 15) * 4 + q;
        wp1[e] = packh(m[t * H_ + 2 * j], m[t * H_ + 2 * j + 1]);
    } else if (gid < 163840) {
        int e = gid - 98304;
        int q = e & 3, t = (e >> 2) & 511, j4 = e >> 11;
        const float* m = (j4 < 16) ? w_ih2 : w_hh2;
        int j = (j4 & 15) * 4 + q;
        wp2[e] = packh(m[t * H_ + 2 * j], m[t * H_ + 2 * j + 1]);
    }
}

// ---------------------------------------------------------------------------
// Kernel A: pred_t + mkx precompute.  One thread per (b,l,k) item.
// ---------------------------------------------------------------------------
extern "C" __global__ void __launch_bounds__(256)
kA(const int* __restrict__ x, const int* __restrict__ dpt, const int* __restrict__ adj,
   const float* __restrict__ eprop, const float* __restrict__ x_emb,
   const float* __restrict__ t_emb, const float* __restrict__ tcost,
   const float* __restrict__ wat, const float* __restrict__ bat,
   const float* __restrict__ wmx, const float* __restrict__ bmx,
   const float* __restrict__ wmt, const float* __restrict__ bmt,
   float* __restrict__ mkx_ws, float* __restrict__ pred_t)
{
    int gid = blockIdx.x * 256 + threadIdx.x;
    if (gid >= B_ * L_ * K_) return;
    int k  = gid % K_;
    int bl = gid / K_;
    int xt = x[bl];
    int dt = dpt[bl];
    int a  = adj[xt * K_ + k];

    float accx[OD], acct[OD];
#pragma unroll
    for (int o = 0; o < OD; ++o) { accx[o] = 0.f; acct[o] = 0.f; }

    for (int d = 0; d < XE; d += 4) {
        float4 m4 = *(const float4*)(x_emb + (size_t)a * XE + d);
        float mv[4] = {m4.x, m4.y, m4.z, m4.w};
#pragma unroll
        for (int q = 0; q < 4; ++q)
#pragma unroll
            for (int o = 0; o < OD; ++o) {
                accx[o] = fmaf(mv[q], wmx[o * MKD + d + q], accx[o]);
                acct[o] = fmaf(mv[q], wmt[o * MKD + d + q], acct[o]);
            }
    }
    for (int d = 0; d < TE; d += 4) {
        float4 m4 = *(const float4*)(t_emb + (size_t)dt * TE + d);
        float mv[4] = {m4.x, m4.y, m4.z, m4.w};
#pragma unroll
        for (int q = 0; q < 4; ++q)
#pragma unroll
            for (int o = 0; o < OD; ++o) {
                accx[o] = fmaf(mv[q], wmx[o * MKD + XE + d + q], accx[o]);
                acct[o] = fmaf(mv[q], wmt[o * MKD + XE + d + q], acct[o]);
            }
    }
    {
        float4 m4a = *(const float4*)(eprop + (size_t)a * EP);
        float4 m4b = *(const float4*)(eprop + (size_t)a * EP + 4);
        float mv[8] = {m4a.x, m4a.y, m4a.z, m4a.w, m4b.x, m4b.y, m4b.z, m4b.w};
#pragma unroll
        for (int q = 0; q < 8; ++q)
#pragma unroll
            for (int o = 0; o < OD; ++o) {
                accx[o] = fmaf(mv[q], wmx[o * MKD + XE + TE + q], accx[o]);
                acct[o] = fmaf(mv[q], wmt[o * MKD + XE + TE + q], acct[o]);
            }
    }

    float* mout = mkx_ws + (size_t)gid * OD;
#pragma unroll
    for (int o = 0; o < OD; ++o) mout[o] = accx[o] + bmx[o];

    float acca[OD];
#pragma unroll
    for (int o = 0; o < OD; ++o) acca[o] = 0.f;
    for (int d = 0; d < TE; d += 4) {
        float4 m4 = *(const float4*)(tcost + (size_t)a * TE + d);
        float mv[4] = {m4.x, m4.y, m4.z, m4.w};
#pragma unroll
        for (int q = 0; q < 4; ++q)
#pragma unroll
            for (int o = 0; o < OD; ++o)
                acca[o] = fmaf(mv[q], wat[o * 64 + d + q], acca[o]);
    }
    for (int d = 0; d < TE; d += 4) {
        float4 m4 = *(const float4*)(t_emb + (size_t)dt * TE + d);
        float mv[4] = {m4.x, m4.y, m4.z, m4.w};
#pragma unroll
        for (int q = 0; q < 4; ++q)
#pragma unroll
            for (int o = 0; o < OD; ++o)
                acca[o] = fmaf(mv[q], wat[o * 64 + TE + d + q], acca[o]);
    }

    float pt = 0.f;
#pragma unroll
    for (int o = 0; o < OD; ++o) {
        float at = acca[o] + bat[o];
        at = at > 0.f ? at : 0.f;
        float mt = acct[o] + bmt[o];
        pt = fmaf(at, mt, pt);
    }
    pred_t[gid] = 1.f / (1.f + expf(-pt));
}

// ---------------------------------------------------------------------------
// Kernel P0: g0[bl][512] = hid @ w_ih0.T + b_ih0 + b_hh0.
// ---------------------------------------------------------------------------
extern "C" __global__ void __launch_bounds__(256)
kP0(const int* __restrict__ x, const int* __restrict__ dpt,
    const float* __restrict__ z, const float* __restrict__ eprop,
    const float* __restrict__ x_emb, const float* __restrict__ t_emb,
    const float* __restrict__ w_ih0, const float* __restrict__ b_ih0,
    const float* __restrict__ b_hh0, float* __restrict__ g0)
{
    int wid   = (blockIdx.x * 256 + threadIdx.x) >> 6;
    int lane  = threadIdx.x & 63;
    int chunk = wid & 7;
    int grp   = wid >> 3;
    int bl    = grp * 64 + lane;
    int b     = bl >> 7;
    int l     = bl & 127;
    int xt = x[bl];
    int dt = dpt[bl];

    float acc[64];
#pragma unroll
    for (int j = 0; j < 64; ++j) acc[j] = 0.f;
    const float* wbase = w_ih0 + (size_t)(chunk * 64) * IN0;

    for (int d = 0; d < ZD; d += 4) {
        float4 m4 = *(const float4*)(z + ((size_t)l * B_ + b) * ZD + d);
        float mv[4] = {m4.x, m4.y, m4.z, m4.w};
#pragma unroll
        for (int q = 0; q < 4; ++q)
#pragma unroll
            for (int j = 0; j < 64; ++j)
                acc[j] = fmaf(mv[q], wbase[j * IN0 + d + q], acc[j]);
    }
    for (int d = 0; d < XE; d += 4) {
        float4 m4 = *(const float4*)(x_emb + (size_t)xt * XE + d);
        float mv[4] = {m4.x, m4.y, m4.z, m4.w};
#pragma unroll
        for (int q = 0; q < 4; ++q)
#pragma unroll
            for (int j = 0; j < 64; ++j)
                acc[j] = fmaf(mv[q], wbase[j * IN0 + ZD + d + q], acc[j]);
    }
    for (int d = 0; d < TE; d += 4) {
        float4 m4 = *(const float4*)(t_emb + (size_t)dt * TE + d);
        float mv[4] = {m4.x, m4.y, m4.z, m4.w};
#pragma unroll
        for (int q = 0; q < 4; ++q)
#pragma unroll
            for (int j = 0; j < 64; ++j)
                acc[j] = fmaf(mv[q], wbase[j * IN0 + ZD + XE + d + q], acc[j]);
    }
    {
        float4 m4a = *(const float4*)(eprop + (size_t)xt * EP);
        float4 m4b = *(const float4*)(eprop + (size_t)xt * EP + 4);
        float mv[8] = {m4a.x, m4a.y, m4a.z, m4a.w, m4b.x, m4b.y, m4b.z, m4b.w};
#pragma unroll
        for (int q = 0; q < 8; ++q)
#pragma unroll
            for (int j = 0; j < 64; ++j)
                acc[j] = fmaf(mv[q], wbase[j * IN0 + ZD + XE + TE + q], acc[j]);
    }

    float* gout = g0 + (size_t)bl * G4 + chunk * 64;
#pragma unroll
    for (int j = 0; j < 64; ++j)
        gout[j] = acc[j] + b_ih0[chunk * 64 + j] + b_hh0[chunk * 64 + j];
}

// ---------------------------------------------------------------------------
// Kernel S2: sequential 3-layer LSTM.  256 blocks x 512 threads, RB2=2 rows
// per block.  Weights: packed f16 pairs, [j4][512 gates][4] coalesced uint4.
// h kept in LDS as packed f16; c in fp32.  dot via v_dot2_f32_f16.
// ---------------------------------------------------------------------------
extern "C" __global__ void __launch_bounds__(512, 2)
kS2(const float* __restrict__ g0,
    const uint4* __restrict__ wp0, const uint4* __restrict__ wp1,
    const uint4* __restrict__ wp2,
    const float* __restrict__ b_ih1, const float* __restrict__ b_hh1,
    const float* __restrict__ b_ih2, const float* __restrict__ b_hh2,
    float* __restrict__ h2s)
{
    __shared__ u32 sh0[RB2][64], sh1[RB2][64], sh2[RB2][64];   // packed f16 h
    __shared__ float sc0[RB2][H_], sc1[RB2][H_], sc2[RB2][H_];
    __shared__ float sg[RB2][G4];

    const int t  = threadIdx.x;
    const int b0 = blockIdx.x * RB2;

    if (t < 128) { ((u32*)sh0)[t] = 0; ((u32*)sh1)[t] = 0; ((u32*)sh2)[t] = 0; }
    if (t < 256) { ((float*)sc0)[t] = 0.f; ((float*)sc1)[t] = 0.f; ((float*)sc2)[t] = 0.f; }
    __syncthreads();

    const float bL1 = b_ih1[t] + b_hh1[t];
    const float bL2 = b_ih2[t] + b_hh2[t];
    const int r_  = t >> 7;      // update-phase row (t < 256)
    const int hd_ = t & (H_ - 1);

    const uint4* sh0v = (const uint4*)sh0;   // [2*16]
    const uint4* sh1v = (const uint4*)sh1;
    const uint4* sh2v = (const uint4*)sh2;

    for (int l = 0; l < L_; ++l) {
        // ---- layer 0 gates ----
        {
            float a0 = g0[((size_t)(b0 + 0) * L_ + l) * G4 + t];
            float a1 = g0[((size_t)(b0 + 1) * L_ + l) * G4 + t];
#pragma unroll
            for (int j4 = 0; j4 < 16; ++j4) {
                uint4 w  = wp0[j4 * 512 + t];
                uint4 ha = sh0v[j4];
                uint4 hb = sh0v[16 + j4];
                a0 = dot2f(w.x, ha.x, a0); a0 = dot2f(w.y, ha.y, a0);
                a0 = dot2f(w.z, ha.z, a0); a0 = dot2f(w.w, ha.w, a0);
                a1 = dot2f(w.x, hb.x, a1); a1 = dot2f(w.y, hb.y, a1);
                a1 = dot2f(w.z, hb.z, a1); a1 = dot2f(w.w, hb.w, a1);
            }
            sg[0][t] = a0; sg[1][t] = a1;
        }
        __syncthreads();
        if (t < 256) {
            float gi = sg[r_][hd_], gf = sg[r_][H_ + hd_];
            float gg = sg[r_][2 * H_ + hd_], go = sg[r_][3 * H_ + hd_];
            float c = sigm(gf) * sc0[r_][hd_] + sigm(gi) * tanh_f(gg);
            float h = sigm(go) * tanh_f(c);
            sc0[r_][hd_] = c;
            ((__half*)sh0)[r_ * H_ + hd_] = __float2half(h);
        }
        __syncthreads();
        // ---- layer 1 gates ----
        {
            float a0 = bL1, a1 = bL1;
#pragma unroll
            for (int j4 = 0; j4 < 16; ++j4) {
                uint4 w  = wp1[j4 * 512 + t];
                uint4 ha = sh0v[j4];
                uint4 hb = sh0v[16 + j4];
                a0 = dot2f(w.x, ha.x, a0); a0 = dot2f(w.y, ha.y, a0);
                a0 = dot2f(w.z, ha.z, a0); a0 = dot2f(w.w, ha.w, a0);
                a1 = dot2f(w.x, hb.x, a1); a1 = dot2f(w.y, hb.y, a1);
                a1 = dot2f(w.z, hb.z, a1); a1 = dot2f(w.w, hb.w, a1);
            }
#pragma unroll
            for (int j4 = 0; j4 < 16; ++j4) {
                uint4 w  = wp1[(16 + j4) * 512 + t];
                uint4 ha = sh1v[j4];
                uint4 hb = sh1v[16 + j4];
                a0 = dot2f(w.x, ha.x, a0); a0 = dot2f(w.y, ha.y, a0);
                a0 = dot2f(w.z, ha.z, a0); a0 = dot2f(w.w, ha.w, a0);
                a1 = dot2f(w.x, hb.x, a1); a1 = dot2f(w.y, hb.y, a1);
                a1 = dot2f(w.z, hb.z, a1); a1 = dot2f(w.w, hb.w, a1);
            }
            sg[0][t] = a0; sg[1][t] = a1;
        }
        __syncthreads();
        if (t < 256) {
            float gi = sg[r_][hd_], gf = sg[r_][H_ + hd_];
            float gg = sg[r_][2 * H_ + hd_], go = sg[r_][3 * H_ + hd_];
            float c = sigm(gf) * sc1[r_][hd_] + sigm(gi) * tanh_f(gg);
            float h = sigm(go) * tanh_f(c);
            sc1[r_][hd_] = c;
            ((__half*)sh1)[r_ * H_ + hd_] = __float2half(h);
        }
        __syncthreads();
        // ---- layer 2 gates ----
        {
            float a0 = bL2, a1 = bL2;
#pragma unroll
            for (int j4 = 0; j4 < 16; ++j4) {
                uint4 w  = wp2[j4 * 512 + t];
                uint4 ha = sh1v[j4];
                uint4 hb = sh1v[16 + j4];
                a0 = dot2f(w.x, ha.x, a0); a0 = dot2f(w.y, ha.y, a0);
                a0 = dot2f(w.z, ha.z, a0); a0 = dot2f(w.w, ha.w, a0);
                a1 = dot2f(w.x, hb.x, a1); a1 = dot2f(w.y, hb.y, a1);
                a1 = dot2f(w.z, hb.z, a1); a1 = dot2f(w.w, hb.w, a1);
            }
#pragma unroll
            for (int j4 = 0; j4 < 16; ++j4) {
                uint4 w  = wp2[(16 + j4) * 512 + t];
                uint4 ha = sh2v[j4];
                uint4 hb = sh2v[16 + j4];
                a0 = dot2f(w.x, ha.x, a0); a0 = dot2f(w.y, ha.y, a0);
                a0 = dot2f(w.z, ha.z, a0); a0 = dot2f(w.w, ha.w, a0);
                a1 = dot2f(w.x, hb.x, a1); a1 = dot2f(w.y, hb.y, a1);
                a1 = dot2f(w.z, hb.z, a1); a1 = dot2f(w.w, hb.w, a1);
            }
            sg[0][t] = a0; sg[1][t] = a1;
        }
        __syncthreads();
        if (t < 256) {
            float gi = sg[r_][hd_], gf = sg[r_][H_ + hd_];
            float gg = sg[r_][2 * H_ + hd_], go = sg[r_][3 * H_ + hd_];
            float c = sigm(gf) * sc2[r_][hd_] + sigm(gi) * tanh_f(gg);
            float h = sigm(go) * tanh_f(c);
            sc2[r_][hd_] = c;
            ((__half*)sh2)[r_ * H_ + hd_] = __float2half(h);
            h2s[((size_t)(b0 + r_) * L_ + l) * H_ + hd_] = h;
        }
        __syncthreads();
    }
}

// ---------------------------------------------------------------------------
// Kernel X: afterx = relu(h2 @ wax.T + bax); px = afterx . mkx; log_softmax.
// ---------------------------------------------------------------------------
extern "C" __global__ void __launch_bounds__(256)
kX(const int* __restrict__ x, const int* __restrict__ adj,
   const float* __restrict__ wax, const float* __restrict__ bax,
   const float* __restrict__ h2s, const float* __restrict__ mkx_ws,
   float* __restrict__ pred_x)
{
    int bl = blockIdx.x * 256 + threadIdx.x;
    float afterx[OD];
#pragma unroll
    for (int o = 0; o < OD; ++o) afterx[o] = 0.f;

    const float* h2 = h2s + (size_t)bl * H_;
    for (int d = 0; d < H_; d += 4) {
        float4 m4 = *(const float4*)(h2 + d);
        float mv[4] = {m4.x, m4.y, m4.z, m4.w};
#pragma unroll
        for (int q = 0; q < 4; ++q)
#pragma unroll
            for (int o = 0; o < OD; ++o)
                afterx[o] = fmaf(mv[q], wax[o * H_ + d + q], afterx[o]);
    }
#pragma unroll
    for (int o = 0; o < OD; ++o) {
        float v = afterx[o] + bax[o];
        afterx[o] = v > 0.f ? v : 0.f;
    }

    int xt = x[bl];
    float px[K_];
#pragma unroll
    for (int k = 0; k < K_; ++k) {
        const float* mv = mkx_ws + (size_t)bl * (K_ * OD) + k * OD;
        float s = 0.f;
#pragma unroll
        for (int o = 0; o < OD; o += 4) {
            float4 m4 = *(const float4*)(mv + o);
            s += afterx[o] * m4.x + afterx[o + 1] * m4.y
               + afterx[o + 2] * m4.z + afterx[o + 3] * m4.w;
        }
        int a = adj[xt * K_ + k];
        px[k] = (a == NE) ? -INFINITY : s;
    }

    float m = px[0];
#pragma unroll
    for (int k = 1; k < K_; ++k) m = fmaxf(m, px[k]);
    float ssum = 0.f;
#pragma unroll
    for (int k = 0; k < K_; ++k) ssum += expf(px[k] - m);
    float lse = logf(ssum) + m;
#pragma unroll
    for (int k = 0; k < K_; ++k)
        pred_x[(size_t)bl * K_ + k] = px[k] - lse;
}

// ---------------------------------------------------------------------------
extern "C" void kernel_launch(void* const* d_in, const int* in_sizes, int n_in,
                              void* d_out, int out_size, void* d_ws, size_t ws_size,
                              hipStream_t stream)
{
    (void)in_sizes; (void)n_in; (void)out_size; (void)ws_size;

    const int*   x      = (const int*)  d_in[0];
    const int*   dpt    = (const int*)  d_in[1];
    const float* z      = (const float*)d_in[2];
    const int*   adj    = (const int*)  d_in[3];
    const float* eprop  = (const float*)d_in[4];
    const float* x_emb  = (const float*)d_in[5];
    const float* t_emb  = (const float*)d_in[6];
    const float* tcost  = (const float*)d_in[7];
    const float* w_ih0  = (const float*)d_in[8];
    const float* w_hh0  = (const float*)d_in[9];
    const float* b_ih0  = (const float*)d_in[10];
    const float* b_hh0  = (const float*)d_in[11];
    const float* w_ih1  = (const float*)d_in[12];
    const float* w_hh1  = (const float*)d_in[13];
    const float* b_ih1  = (const float*)d_in[14];
    const float* b_hh1  = (const float*)d_in[15];
    const float* w_ih2  = (const float*)d_in[16];
    const float* w_hh2  = (const float*)d_in[17];
    const float* b_ih2  = (const float*)d_in[18];
    const float* b_hh2  = (const float*)d_in[19];
    const float* wax    = (const float*)d_in[20];
    const float* bax    = (const float*)d_in[21];
    const float* wat    = (const float*)d_in[22];
    const float* bat    = (const float*)d_in[23];
    const float* wmx    = (const float*)d_in[24];
    const float* bmx    = (const float*)d_in[25];
    const float* wmt    = (const float*)d_in[26];
    const float* bmt    = (const float*)d_in[27];

    float* out    = (float*)d_out;
    float* pred_x = out;
    float* pred_t = out + (size_t)B_ * L_ * K_;

    float* ws  = (float*)d_ws;
    float* mkx = ws;                                      // B*L*K*32
    float* g0  = mkx + (size_t)B_ * L_ * K_ * OD;         // B*L*512
    float* h2s = g0  + (size_t)B_ * L_ * G4;              // B*L*128
    u32*   wp0 = (u32*)(h2s + (size_t)B_ * L_ * H_);      // 32768 u32
    u32*   wp1 = wp0 + 32768;                             // 65536 u32
    u32*   wp2 = wp1 + 65536;                             // 65536 u32

    hipLaunchKernelGGL(kW, dim3(640), dim3(256), 0, stream,
                       w_hh0, w_ih1, w_hh1, w_ih2, w_hh2, wp0, wp1, wp2);

    hipLaunchKernelGGL(kA, dim3((B_ * L_ * K_) / 256), dim3(256), 0, stream,
                       x, dpt, adj, eprop, x_emb, t_emb, tcost,
                       wat, bat, wmx, bmx, wmt, bmt, mkx, pred_t);

    hipLaunchKernelGGL(kP0, dim3((B_ * L_ * 8) / 256), dim3(256), 0, stream,
                       x, dpt, z, eprop, x_emb, t_emb, w_ih0, b_ih0, b_hh0, g0);

    hipLaunchKernelGGL(kS2, dim3(B_ / RB2), dim3(512), 0, stream,
                       g0, (const uint4*)wp0, (const uint4*)wp1, (const uint4*)wp2,
                       b_ih1, b_hh1, b_ih2, b_hh2, h2s);

    hipLaunchKernelGGL(kX, dim3((B_ * L_) / 256), dim3(256), 0, stream,
                       x, adj, wax, bax, h2s, mkx, pred_x);
}

// Round 3
// 1203.877 us; speedup vs baseline: 5.6686x; 3.5011x over previous
//
#include <hip/hip_runtime.h>
#include <hip/hip_fp16.h>
#include <math.h>
#include <stdint.h>

#define B_   512
#define L_   128
#define K_   9
#define NE   50000
#define ZD   16
#define TE   32
#define XE   128
#define EP   8
#define H_   128
#define G4   512
#define OD   32
#define IN0  184
#define MKD  168

typedef uint32_t u32;
typedef _Float16 half2v __attribute__((ext_vector_type(2)));

__device__ __forceinline__ float sigm(float x) {
    x = fminf(fmaxf(x, -30.f), 30.f);
    return 1.f / (1.f + expf(-x));
}
__device__ __forceinline__ float tanh_f(float x) {
    x = fminf(fmaxf(x, -15.f), 15.f);
    float e = expf(2.f * x);
    return (e - 1.f) / (e + 1.f);
}
__device__ __forceinline__ float dot2f(u32 w, u32 h, float acc) {
#if __has_builtin(__builtin_amdgcn_fdot2)
    union { u32 u; half2v v; } a, b;
    a.u = w; b.u = h;
    return __builtin_amdgcn_fdot2(a.v, b.v, acc, false);
#else
    union { u32 u; __half2 h2; } a, b;
    a.u = w; b.u = h;
    float2 fa = __half22float2(a.h2), fb = __half22float2(b.h2);
    return fmaf(fa.x, fb.x, fmaf(fa.y, fb.y, acc));
#endif
}
__device__ __forceinline__ float dot4(uint4 w, uint4 h, float acc) {
    acc = dot2f(w.x, h.x, acc); acc = dot2f(w.y, h.y, acc);
    acc = dot2f(w.z, h.z, acc); acc = dot2f(w.w, h.w, acc);
    return acc;
}
__device__ __forceinline__ u32 packh(float lo, float hi) {
    union { __half2 h; u32 u; } p;
    p.h = __halves2half2(__float2half(lo), __float2half(hi));
    return p.u;
}
__device__ __forceinline__ float halfsel(u32 p, int hi) {
    union { u32 u; __half2 h; } v; v.u = p;
    return __half2float(hi ? __high2half(v.h) : __low2half(v.h));
}

// ---------------------------------------------------------------------------
// kW: pack weights to f16 pairs.
//  wp0 [16 j4][512 gate][4]  <- w_hh0          (32768 u32)
//  wp1 [32 j4][512][4]       <- w_ih1|w_hh1    (65536)
//  wp2 [32 j4][512][4]       <- w_ih2|w_hh2    (65536)
//  w_ih0p [512 gate][92]     <- w_ih0          (47104)
//  wap [32 o][64]            <- wax            (2048)
//  wmxp [32 o][68]           <- wmx cols {0..127,160..167}  (2176)
//  wmtp [32 o][68]           <- wmt same cols               (2176)
//  watp0 [32 o][16]          <- wat cols 0..31              (512)
// ---------------------------------------------------------------------------
extern "C" __global__ void __launch_bounds__(256)
kW(const float* __restrict__ w_hh0,
   const float* __restrict__ w_ih1, const float* __restrict__ w_hh1,
   const float* __restrict__ w_ih2, const float* __restrict__ w_hh2,
   const float* __restrict__ w_ih0, const float* __restrict__ wax,
   const float* __restrict__ wmx, const float* __restrict__ wmt,
   const float* __restrict__ wat,
   u32* __restrict__ wp0, u32* __restrict__ wp1, u32* __restrict__ wp2,
   u32* __restrict__ w_ih0p, u32* __restrict__ wap,
   u32* __restrict__ wmxp, u32* __restrict__ wmtp, u32* __restrict__ watp0)
{
    int gid = blockIdx.x * 256 + threadIdx.x;
    if (gid < 32768) {
        int e = gid; int q = e & 3, t = (e >> 2) & 511, j4 = e >> 11;
        int j = j4 * 4 + q;
        wp0[e] = packh(w_hh0[t * H_ + 2 * j], w_hh0[t * H_ + 2 * j + 1]);
    } else if (gid < 98304) {
        int e = gid - 32768;
        int q = e & 3, t = (e >> 2) & 511, j4 = e >> 11;
        const float* m = (j4 < 16) ? w_ih1 : w_hh1;
        int j = (j4 & 15) * 4 + q;
        wp1[e] = packh(m[t * H_ + 2 * j], m[t * H_ + 2 * j + 1]);
    } else if (gid < 163840) {
        int e = gid - 98304;
        int q = e & 3, t = (e >> 2) & 511, j4 = e >> 11;
        const float* m = (j4 < 16) ? w_ih2 : w_hh2;
        int j = (j4 & 15) * 4 + q;
        wp2[e] = packh(m[t * H_ + 2 * j], m[t * H_ + 2 * j + 1]);
    } else if (gid < 210944) {
        int e = gid - 163840;
        int g = e / 92, c = e % 92;
        w_ih0p[e] = packh(w_ih0[g * IN0 + 2 * c], w_ih0[g * IN0 + 2 * c + 1]);
    } else if (gid < 212992) {
        int e = gid - 210944; int o = e >> 6, c = e & 63;
        wap[e] = packh(wax[o * H_ + 2 * c], wax[o * H_ + 2 * c + 1]);
    } else if (gid < 215168) {
        int e = gid - 212992; int o = e / 68, c = e % 68;
        int col = c < 64 ? 2 * c : 160 + 2 * (c - 64);
        wmxp[e] = packh(wmx[o * MKD + col], wmx[o * MKD + col + 1]);
    } else if (gid < 217344) {
        int e = gid - 215168; int o = e / 68, c = e % 68;
        int col = c < 64 ? 2 * c : 160 + 2 * (c - 64);
        wmtp[e] = packh(wmt[o * MKD + col], wmt[o * MKD + col + 1]);
    } else if (gid < 217856) {
        int e = gid - 217344; int o = e >> 4, c = e & 15;
        watp0[e] = packh(wat[o * 64 + 2 * c], wat[o * 64 + 2 * c + 1]);
    }
}

// ---------------------------------------------------------------------------
// kT: dt tables (48 x 96): [tmx(+bmx) | tmt(+bmt) | tat(+bat)]
// ---------------------------------------------------------------------------
extern "C" __global__ void __launch_bounds__(256)
kT(const float* __restrict__ t_emb,
   const float* __restrict__ wmx, const float* __restrict__ wmt,
   const float* __restrict__ wat,
   const float* __restrict__ bmx, const float* __restrict__ bmt,
   const float* __restrict__ bat, float* __restrict__ ttab)
{
    int gid = blockIdx.x * 256 + threadIdx.x;
    if (gid >= 48 * 96) return;
    int dt = gid / 96, o96 = gid % 96;
    const float* te = t_emb + dt * TE;
    int o = o96 & 31;
    float acc;
    const float* w;
    if (o96 < 32)      { acc = bmx[o]; w = wmx + o * MKD + XE; }
    else if (o96 < 64) { acc = bmt[o]; w = wmt + o * MKD + XE; }
    else               { acc = bat[o]; w = wat + o * 64 + TE; }
    for (int d = 0; d < TE; ++d) acc = fmaf(te[d], w[d], acc);
    ttab[dt * 96 + o96] = acc;
}

// ---------------------------------------------------------------------------
// kE: per-edge tables (50000 x 96): [emx | emt | eat]  (no biases)
// ---------------------------------------------------------------------------
extern "C" __global__ void __launch_bounds__(256)
kE(const float* __restrict__ x_emb, const float* __restrict__ eprop,
   const float* __restrict__ tcost,
   const u32* __restrict__ wmxp, const u32* __restrict__ wmtp,
   const u32* __restrict__ watp0, float* __restrict__ etab)
{
    __shared__ uint4 smx[544], smt[544], sat[128];
    int tid = threadIdx.x;
    for (int i = tid; i < 544; i += 256) {
        smx[i] = ((const uint4*)wmxp)[i];
        smt[i] = ((const uint4*)wmtp)[i];
    }
    if (tid < 128) sat[tid] = ((const uint4*)watp0)[tid];
    __syncthreads();
    int e = blockIdx.x * 256 + tid;
    if (e >= NE) return;

    u32 in[68], tin[16];
    const float* xr = x_emb + (size_t)e * XE;
#pragma unroll
    for (int c = 0; c < 64; ++c) in[c] = packh(xr[2 * c], xr[2 * c + 1]);
    const float* er = eprop + (size_t)e * EP;
#pragma unroll
    for (int c = 0; c < 4; ++c) in[64 + c] = packh(er[2 * c], er[2 * c + 1]);
    const float* tr = tcost + (size_t)e * TE;
#pragma unroll
    for (int c = 0; c < 16; ++c) tin[c] = packh(tr[2 * c], tr[2 * c + 1]);

    float* outp = etab + (size_t)e * 96;
    for (int o = 0; o < OD; ++o) {
        float ax = 0.f, am = 0.f, aa = 0.f;
#pragma unroll
        for (int c4 = 0; c4 < 17; ++c4) {
            uint4 wx = smx[o * 17 + c4], wt = smt[o * 17 + c4];
            ax = dot2f(wx.x, in[c4 * 4 + 0], ax);
            ax = dot2f(wx.y, in[c4 * 4 + 1], ax);
            ax = dot2f(wx.z, in[c4 * 4 + 2], ax);
            ax = dot2f(wx.w, in[c4 * 4 + 3], ax);
            am = dot2f(wt.x, in[c4 * 4 + 0], am);
            am = dot2f(wt.y, in[c4 * 4 + 1], am);
            am = dot2f(wt.z, in[c4 * 4 + 2], am);
            am = dot2f(wt.w, in[c4 * 4 + 3], am);
        }
#pragma unroll
        for (int c4 = 0; c4 < 4; ++c4) {
            uint4 wa = sat[o * 4 + c4];
            aa = dot2f(wa.x, tin[c4 * 4 + 0], aa);
            aa = dot2f(wa.y, tin[c4 * 4 + 1], aa);
            aa = dot2f(wa.z, tin[c4 * 4 + 2], aa);
            aa = dot2f(wa.w, tin[c4 * 4 + 3], aa);
        }
        outp[o] = ax; outp[32 + o] = am; outp[64 + o] = aa;
    }
}

// ---------------------------------------------------------------------------
// kP0v2: g0h[bl][512] (f16) = hid @ w_ih0.T + b_ih0 + b_hh0.
// 512 threads = 512 gates; weight row in registers; A-panel (128 items) in LDS.
// ---------------------------------------------------------------------------
extern "C" __global__ void __launch_bounds__(512)
kP0v2(const int* __restrict__ x, const int* __restrict__ dpt,
      const float* __restrict__ z, const float* __restrict__ eprop,
      const float* __restrict__ x_emb, const float* __restrict__ t_emb,
      const u32* __restrict__ w_ih0p,
      const float* __restrict__ b_ih0, const float* __restrict__ b_hh0,
      __half* __restrict__ g0h)
{
    __shared__ u32 aTT[128 * 92];
    int tid = threadIdx.x;
    int bl0 = blockIdx.x * 128;

    uint4 w4[23];
#pragma unroll
    for (int c4 = 0; c4 < 23; ++c4)
        w4[c4] = ((const uint4*)w_ih0p)[tid * 23 + c4];
    float bias = b_ih0[tid] + b_hh0[tid];

    {
        int i = tid >> 2, q = tid & 3;
        int bl = bl0 + i;
        int xt = x[bl], dt = dpt[bl];
        int b = bl >> 7, l = bl & 127;
        const float* zr = z + ((size_t)l * B_ + b) * ZD;
        const float* xr = x_emb + (size_t)xt * XE;
        const float* tr = t_emb + (size_t)dt * TE;
        const float* er = eprop + (size_t)xt * EP;
#pragma unroll
        for (int cc = 0; cc < 23; ++cc) {
            int c = q * 23 + cc;
            float lo, hi;
            if (c < 8)       { lo = zr[2 * c];            hi = zr[2 * c + 1]; }
            else if (c < 72) { lo = xr[2 * (c - 8)];      hi = xr[2 * (c - 8) + 1]; }
            else if (c < 88) { lo = tr[2 * (c - 72)];     hi = tr[2 * (c - 72) + 1]; }
            else             { lo = er[2 * (c - 88)];     hi = er[2 * (c - 88) + 1]; }
            aTT[i * 92 + c] = packh(lo, hi);
        }
    }
    __syncthreads();

    const uint4* a4 = (const uint4*)aTT;
    for (int i = 0; i < 128; i += 4) {
        float acc0 = 0.f, acc1 = 0.f, acc2 = 0.f, acc3 = 0.f;
#pragma unroll
        for (int c4 = 0; c4 < 23; ++c4) {
            uint4 aa0 = a4[(i + 0) * 23 + c4];
            uint4 aa1 = a4[(i + 1) * 23 + c4];
            uint4 aa2 = a4[(i + 2) * 23 + c4];
            uint4 aa3 = a4[(i + 3) * 23 + c4];
            acc0 = dot4(w4[c4], aa0, acc0);
            acc1 = dot4(w4[c4], aa1, acc1);
            acc2 = dot4(w4[c4], aa2, acc2);
            acc3 = dot4(w4[c4], aa3, acc3);
        }
        g0h[(size_t)(bl0 + i + 0) * G4 + tid] = __float2half(acc0 + bias);
        g0h[(size_t)(bl0 + i + 1) * G4 + tid] = __float2half(acc1 + bias);
        g0h[(size_t)(bl0 + i + 2) * G4 + tid] = __float2half(acc2 + bias);
        g0h[(size_t)(bl0 + i + 3) * G4 + tid] = __float2half(acc3 + bias);
    }
}

// ---------------------------------------------------------------------------
// kL0: layer-0 recurrence.  256 blocks x 512 threads; 2 batch rows/block.
// w_hh0 row in registers (16 uint4); h packed f16 in LDS; c in registers.
// ---------------------------------------------------------------------------
extern "C" __global__ void __launch_bounds__(512)
kL0(const __half* __restrict__ g0h, const u32* __restrict__ wp0,
    __half* __restrict__ h0seq)
{
    __shared__ u32 sh[2][64];
    __shared__ float sg[2][G4];
    int t = threadIdx.x;
    int b0 = blockIdx.x * 2;

    uint4 w4[16];
#pragma unroll
    for (int j4 = 0; j4 < 16; ++j4)
        w4[j4] = ((const uint4*)wp0)[j4 * 512 + t];
    if (t < 128) ((u32*)sh)[t] = 0;

    float c_reg = 0.f;
    int r_ = t >> 7, hd_ = t & 127;
    const u32* g0u = (const u32*)g0h;
    u32 pre0 = g0u[((size_t)(b0 + 0) * L_ + 0) * 256 + (t >> 1)];
    u32 pre1 = g0u[((size_t)(b0 + 1) * L_ + 0) * 256 + (t >> 1)];
    __syncthreads();

    for (int l = 0; l < L_; ++l) {
        int ln = l < 127 ? l + 1 : 127;
        u32 n0 = g0u[((size_t)(b0 + 0) * L_ + ln) * 256 + (t >> 1)];
        u32 n1 = g0u[((size_t)(b0 + 1) * L_ + ln) * 256 + (t >> 1)];
        float a0 = halfsel(pre0, t & 1), a1 = halfsel(pre1, t & 1);
        const uint4* s0 = (const uint4*)&sh[0][0];
        const uint4* s1 = (const uint4*)&sh[1][0];
#pragma unroll
        for (int j4 = 0; j4 < 16; ++j4) {
            a0 = dot4(w4[j4], s0[j4], a0);
            a1 = dot4(w4[j4], s1[j4], a1);
        }
        sg[0][t] = a0; sg[1][t] = a1;
        __syncthreads();
        if (t < 256) {
            float gi = sg[r_][hd_], gf = sg[r_][H_ + hd_];
            float gg = sg[r_][2 * H_ + hd_], go = sg[r_][3 * H_ + hd_];
            float c = sigm(gf) * c_reg + sigm(gi) * tanh_f(gg);
            float h = sigm(go) * tanh_f(c);
            c_reg = c;
            __half hh = __float2half(h);
            ((__half*)sh)[r_ * H_ + hd_] = hh;
            h0seq[((size_t)(b0 + r_) * L_ + l) * H_ + hd_] = hh;
        }
        __syncthreads();
        pre0 = n0; pre1 = n1;
    }
}

// ---------------------------------------------------------------------------
// kL12: layers 1/2 recurrence (shared code).  Input h-seq from global (f16),
// w_ih & w_hh rows in registers (32 uint4); double-buffered hprev in LDS.
// ---------------------------------------------------------------------------
extern "C" __global__ void __launch_bounds__(512)
kL12(const __half* __restrict__ hinseq, const u32* __restrict__ wp,
     const float* __restrict__ b_ih, const float* __restrict__ b_hh,
     __half* __restrict__ houtseq)
{
    __shared__ u32 shp[2][2][64];
    __shared__ u32 sh[2][64];
    __shared__ float sg[2][G4];
    int t = threadIdx.x;
    int b0 = blockIdx.x * 2;

    uint4 wi[16], wh[16];
#pragma unroll
    for (int j4 = 0; j4 < 16; ++j4) {
        wi[j4] = ((const uint4*)wp)[j4 * 512 + t];
        wh[j4] = ((const uint4*)wp)[(16 + j4) * 512 + t];
    }
    float bias = b_ih[t] + b_hh[t];
    if (t < 128) ((u32*)sh)[t] = 0;

    const u32* hin = (const u32*)hinseq;
    if (t >= 256 && t < 384) {
        int j = t - 256, r = j >> 6, c = j & 63;
        shp[0][r][c] = hin[((size_t)(b0 + r) * L_ + 0) * 64 + c];
    }
    float c_reg = 0.f;
    int r_ = t >> 7, hd_ = t & 127;
    __syncthreads();

    for (int l = 0; l < L_; ++l) {
        u32 nx = 0;
        if (t >= 256 && t < 384) {
            int j = t - 256, r = j >> 6, c = j & 63;
            int ln = l < 127 ? l + 1 : 127;
            nx = hin[((size_t)(b0 + r) * L_ + ln) * 64 + c];
        }
        float a0 = bias, a1 = bias;
        const uint4* p0 = (const uint4*)&shp[l & 1][0][0];
        const uint4* p1 = (const uint4*)&shp[l & 1][1][0];
        const uint4* s0 = (const uint4*)&sh[0][0];
        const uint4* s1 = (const uint4*)&sh[1][0];
#pragma unroll
        for (int j4 = 0; j4 < 16; ++j4) {
            a0 = dot4(wi[j4], p0[j4], a0);
            a1 = dot4(wi[j4], p1[j4], a1);
        }
#pragma unroll
        for (int j4 = 0; j4 < 16; ++j4) {
            a0 = dot4(wh[j4], s0[j4], a0);
            a1 = dot4(wh[j4], s1[j4], a1);
        }
        sg[0][t] = a0; sg[1][t] = a1;
        __syncthreads();
        if (t < 256) {
            float gi = sg[r_][hd_], gf = sg[r_][H_ + hd_];
            float gg = sg[r_][2 * H_ + hd_], go = sg[r_][3 * H_ + hd_];
            float c = sigm(gf) * c_reg + sigm(gi) * tanh_f(gg);
            float h = sigm(go) * tanh_f(c);
            c_reg = c;
            __half hh = __float2half(h);
            ((__half*)sh)[r_ * H_ + hd_] = hh;
            houtseq[((size_t)(b0 + r_) * L_ + l) * H_ + hd_] = hh;
        } else if (t < 384) {
            int j = t - 256, r = j >> 6, c = j & 63;
            shp[(l + 1) & 1][r][c] = nx;
        }
        __syncthreads();
    }
}

// ---------------------------------------------------------------------------
// kX2: fused epilogue.  afterx from h2 (f16 dot2), px/pt from etab+ttab.
// ---------------------------------------------------------------------------
extern "C" __global__ void __launch_bounds__(256)
kX2(const int* __restrict__ x, const int* __restrict__ dpt,
    const int* __restrict__ adj, const __half* __restrict__ h2seq,
    const u32* __restrict__ wap, const float* __restrict__ bax,
    const float* __restrict__ etab, const float* __restrict__ ttab,
    float* __restrict__ pred_x, float* __restrict__ pred_t)
{
    __shared__ uint4 swp[512];
    __shared__ float stt[48 * 96];
    __shared__ float sbax[32];
    int tid = threadIdx.x;
    for (int i = tid; i < 512; i += 256) swp[i] = ((const uint4*)wap)[i];
    for (int i = tid; i < 4608; i += 256) stt[i] = ttab[i];
    if (tid < 32) sbax[tid] = bax[tid];
    __syncthreads();

    int bl = blockIdx.x * 256 + tid;
    int xt = x[bl], dt = dpt[bl];

    uint4 h2r[16];
    const uint4* h2p = (const uint4*)(h2seq + (size_t)bl * H_);
#pragma unroll
    for (int q = 0; q < 16; ++q) h2r[q] = h2p[q];

    float afterx[OD];
    for (int o = 0; o < OD; ++o) {
        float acc = sbax[o];
#pragma unroll
        for (int q = 0; q < 16; ++q) {
            uint4 w = swp[o * 16 + q];
            acc = dot2f(w.x, h2r[q].x, acc);
            acc = dot2f(w.y, h2r[q].y, acc);
            acc = dot2f(w.z, h2r[q].z, acc);
            acc = dot2f(w.w, h2r[q].w, acc);
        }
        afterx[o] = acc > 0.f ? acc : 0.f;
    }

    const float4* tp = (const float4*)(stt + dt * 96);
    float px[K_];
#pragma unroll
    for (int k = 0; k < K_; ++k) {
        int a = adj[xt * K_ + k];
        int ac = a < NE ? a : 0;
        const float4* ep = (const float4*)(etab + (size_t)ac * 96);
        float sx = 0.f, st = 0.f;
#pragma unroll
        for (int q = 0; q < 8; ++q) {
            float4 e = ep[q], tt = tp[q];
            sx += afterx[q * 4 + 0] * (e.x + tt.x)
                + afterx[q * 4 + 1] * (e.y + tt.y)
                + afterx[q * 4 + 2] * (e.z + tt.z)
                + afterx[q * 4 + 3] * (e.w + tt.w);
        }
#pragma unroll
        for (int q = 0; q < 8; ++q) {
            float4 em = ep[8 + q], tm = tp[8 + q];
            float4 ea = ep[16 + q], ta = tp[16 + q];
            float at0 = fmaxf(ea.x + ta.x, 0.f);
            float at1 = fmaxf(ea.y + ta.y, 0.f);
            float at2 = fmaxf(ea.z + ta.z, 0.f);
            float at3 = fmaxf(ea.w + ta.w, 0.f);
            st += at0 * (em.x + tm.x) + at1 * (em.y + tm.y)
                + at2 * (em.z + tm.z) + at3 * (em.w + tm.w);
        }
        px[k] = (a == NE) ? -INFINITY : sx;
        pred_t[(size_t)bl * K_ + k] = 1.f / (1.f + expf(-st));
    }

    float m = px[0];
#pragma unroll
    for (int k = 1; k < K_; ++k) m = fmaxf(m, px[k]);
    float ssum = 0.f;
#pragma unroll
    for (int k = 0; k < K_; ++k) ssum += expf(px[k] - m);
    float lse = logf(ssum) + m;
#pragma unroll
    for (int k = 0; k < K_; ++k)
        pred_x[(size_t)bl * K_ + k] = px[k] - lse;
}

// ---------------------------------------------------------------------------
extern "C" void kernel_launch(void* const* d_in, const int* in_sizes, int n_in,
                              void* d_out, int out_size, void* d_ws, size_t ws_size,
                              hipStream_t stream)
{
    (void)in_sizes; (void)n_in; (void)out_size; (void)ws_size;

    const int*   x      = (const int*)  d_in[0];
    const int*   dpt    = (const int*)  d_in[1];
    const float* z      = (const float*)d_in[2];
    const int*   adj    = (const int*)  d_in[3];
    const float* eprop  = (const float*)d_in[4];
    const float* x_emb  = (const float*)d_in[5];
    const float* t_emb  = (const float*)d_in[6];
    const float* tcost  = (const float*)d_in[7];
    const float* w_ih0  = (const float*)d_in[8];
    const float* w_hh0  = (const float*)d_in[9];
    const float* b_ih0  = (const float*)d_in[10];
    const float* b_hh0  = (const float*)d_in[11];
    const float* w_ih1  = (const float*)d_in[12];
    const float* w_hh1  = (const float*)d_in[13];
    const float* b_ih1  = (const float*)d_in[14];
    const float* b_hh1  = (const float*)d_in[15];
    const float* w_ih2  = (const float*)d_in[16];
    const float* w_hh2  = (const float*)d_in[17];
    const float* b_ih2  = (const float*)d_in[18];
    const float* b_hh2  = (const float*)d_in[19];
    const float* wax    = (const float*)d_in[20];
    const float* bax    = (const float*)d_in[21];
    const float* wat    = (const float*)d_in[22];
    const float* bat    = (const float*)d_in[23];
    const float* wmx    = (const float*)d_in[24];
    const float* bmx    = (const float*)d_in[25];
    const float* wmt    = (const float*)d_in[26];
    const float* bmt    = (const float*)d_in[27];

    float* out    = (float*)d_out;
    float* pred_x = out;
    float* pred_t = out + (size_t)B_ * L_ * K_;

    u32* wsu = (u32*)d_ws;
    u32* wp0    = wsu;                 // 32768
    u32* wp1    = wp0 + 32768;         // 65536
    u32* wp2    = wp1 + 65536;         // 65536
    u32* wih0p  = wp2 + 65536;         // 47104
    u32* wap    = wih0p + 47104;       // 2048
    u32* wmxp   = wap + 2048;          // 2176
    u32* wmtp   = wmxp + 2176;         // 2176
    u32* watp0  = wmtp + 2176;         // 512
    __half* g0h   = (__half*)(watp0 + 512);     // 65536*512
    __half* h0seq = g0h + (size_t)65536 * 512;  // 65536*128
    __half* h1seq = h0seq + (size_t)65536 * 128;
    __half* h2seq = h1seq + (size_t)65536 * 128;
    float*  etab  = (float*)(h2seq + (size_t)65536 * 128);  // 50000*96
    float*  ttab  = etab + (size_t)NE * 96;                 // 4608

    hipLaunchKernelGGL(kW, dim3(851), dim3(256), 0, stream,
                       w_hh0, w_ih1, w_hh1, w_ih2, w_hh2, w_ih0, wax, wmx, wmt, wat,
                       wp0, wp1, wp2, wih0p, wap, wmxp, wmtp, watp0);

    hipLaunchKernelGGL(kT, dim3(18), dim3(256), 0, stream,
                       t_emb, wmx, wmt, wat, bmx, bmt, bat, ttab);

    hipLaunchKernelGGL(kE, dim3(196), dim3(256), 0, stream,
                       x_emb, eprop, tcost, wmxp, wmtp, watp0, etab);

    hipLaunchKernelGGL(kP0v2, dim3(512), dim3(512), 0, stream,
                       x, dpt, z, eprop, x_emb, t_emb, wih0p, b_ih0, b_hh0, g0h);

    hipLaunchKernelGGL(kL0, dim3(256), dim3(512), 0, stream,
                       g0h, wp0, h0seq);

    hipLaunchKernelGGL(kL12, dim3(256), dim3(512), 0, stream,
                       h0seq, wp1, b_ih1, b_hh1, h1seq);

    hipLaunchKernelGGL(kL12, dim3(256), dim3(512), 0, stream,
                       h1seq, wp2, b_ih2, b_hh2, h2seq);

    hipLaunchKernelGGL(kX2, dim3(256), dim3(256), 0, stream,
                       x, dpt, adj, h2seq, wap, bax, etab, ttab, pred_x, pred_t);
}

// Round 4
// 933.398 us; speedup vs baseline: 7.3112x; 1.2898x over previous
//
#include <hip/hip_runtime.h>
#include <hip/hip_fp16.h>
#include <math.h>
#include <stdint.h>

#define B_   512
#define L_   128
#define K_   9
#define NE   50000
#define ZD   16
#define TE   32
#define XE   128
#define EP   8
#define H_   128
#define G4   512
#define OD   32
#define IN0  184
#define MKD  168

typedef uint32_t u32;
typedef _Float16 half2v __attribute__((ext_vector_type(2)));
typedef _Float16 half8  __attribute__((ext_vector_type(8)));
typedef float    f32x4  __attribute__((ext_vector_type(4)));

__device__ __forceinline__ float sigm(float x) {
    x = fminf(fmaxf(x, -30.f), 30.f);
    return 1.f / (1.f + expf(-x));
}
__device__ __forceinline__ float tanh_f(float x) {
    x = fminf(fmaxf(x, -15.f), 15.f);
    float e = expf(2.f * x);
    return (e - 1.f) / (e + 1.f);
}
__device__ __forceinline__ float dot2f(u32 w, u32 h, float acc) {
#if __has_builtin(__builtin_amdgcn_fdot2)
    union { u32 u; half2v v; } a, b;
    a.u = w; b.u = h;
    return __builtin_amdgcn_fdot2(a.v, b.v, acc, false);
#else
    union { u32 u; __half2 h2; } a, b;
    a.u = w; b.u = h;
    float2 fa = __half22float2(a.h2), fb = __half22float2(b.h2);
    return fmaf(fa.x, fb.x, fmaf(fa.y, fb.y, acc));
#endif
}
__device__ __forceinline__ float dot4(uint4 w, uint4 h, float acc) {
    acc = dot2f(w.x, h.x, acc); acc = dot2f(w.y, h.y, acc);
    acc = dot2f(w.z, h.z, acc); acc = dot2f(w.w, h.w, acc);
    return acc;
}
__device__ __forceinline__ u32 packh(float lo, float hi) {
    union { __half2 h; u32 u; } p;
    p.h = __halves2half2(__float2half(lo), __float2half(hi));
    return p.u;
}

// ---------------------------------------------------------------------------
// kW2: pack all weights (f16 pairs) + bias sums.
// Layout (u32 offsets inside one flat region):
//   wih0p [512][96]   (K=192, cols 184..191 zero)       @ 0       (49152)
//   whp0  [512][64]                                      @ 49152  (32768)
//   wih1p [512][64]                                      @ 81920
//   whp1  [512][64]                                      @ 114688
//   wih2p [512][64]                                      @ 147456
//   whp2  [512][64]                                      @ 180224
//   wap   [32][64]                                       @ 212992 (2048)
//   wmxp  [32][68]                                       @ 215040 (2176)
//   wmtp  [32][68]                                       @ 217216 (2176)
//   watp0 [32][16]                                       @ 219392 (512)
//   bsum  [3][512] f32                                   @ 219904 (1536)
// total 221440 u32  (= 865 * 256)
// ---------------------------------------------------------------------------
__global__ void __launch_bounds__(256)
kW2(const float* __restrict__ w_ih0, const float* __restrict__ w_hh0,
    const float* __restrict__ w_ih1, const float* __restrict__ w_hh1,
    const float* __restrict__ w_ih2, const float* __restrict__ w_hh2,
    const float* __restrict__ wax, const float* __restrict__ wmx,
    const float* __restrict__ wmt, const float* __restrict__ wat,
    const float* __restrict__ b_ih0, const float* __restrict__ b_hh0,
    const float* __restrict__ b_ih1, const float* __restrict__ b_hh1,
    const float* __restrict__ b_ih2, const float* __restrict__ b_hh2,
    u32* __restrict__ wsu)
{
    int gid = blockIdx.x * 256 + threadIdx.x;
    if (gid < 49152) {
        int g = gid / 96, c = gid % 96;
        wsu[gid] = (c < 92) ? packh(w_ih0[g * IN0 + 2 * c], w_ih0[g * IN0 + 2 * c + 1]) : 0u;
    } else if (gid < 81920) {
        int e = gid - 49152; int g = e >> 6, c = e & 63;
        wsu[gid] = packh(w_hh0[g * H_ + 2 * c], w_hh0[g * H_ + 2 * c + 1]);
    } else if (gid < 114688) {
        int e = gid - 81920; int g = e >> 6, c = e & 63;
        wsu[gid] = packh(w_ih1[g * H_ + 2 * c], w_ih1[g * H_ + 2 * c + 1]);
    } else if (gid < 147456) {
        int e = gid - 114688; int g = e >> 6, c = e & 63;
        wsu[gid] = packh(w_hh1[g * H_ + 2 * c], w_hh1[g * H_ + 2 * c + 1]);
    } else if (gid < 180224) {
        int e = gid - 147456; int g = e >> 6, c = e & 63;
        wsu[gid] = packh(w_ih2[g * H_ + 2 * c], w_ih2[g * H_ + 2 * c + 1]);
    } else if (gid < 212992) {
        int e = gid - 180224; int g = e >> 6, c = e & 63;
        wsu[gid] = packh(w_hh2[g * H_ + 2 * c], w_hh2[g * H_ + 2 * c + 1]);
    } else if (gid < 215040) {
        int e = gid - 212992; int o = e >> 6, c = e & 63;
        wsu[gid] = packh(wax[o * H_ + 2 * c], wax[o * H_ + 2 * c + 1]);
    } else if (gid < 217216) {
        int e = gid - 215040; int o = e / 68, c = e % 68;
        int col = c < 64 ? 2 * c : 160 + 2 * (c - 64);
        wsu[gid] = packh(wmx[o * MKD + col], wmx[o * MKD + col + 1]);
    } else if (gid < 219392) {
        int e = gid - 217216; int o = e / 68, c = e % 68;
        int col = c < 64 ? 2 * c : 160 + 2 * (c - 64);
        wsu[gid] = packh(wmt[o * MKD + col], wmt[o * MKD + col + 1]);
    } else if (gid < 219904) {
        int e = gid - 219392; int o = e >> 4, c = e & 15;
        wsu[gid] = packh(wat[o * 64 + 2 * c], wat[o * 64 + 2 * c + 1]);
    } else if (gid < 221440) {
        int e = gid - 219904; int layer = e >> 9, g = e & 511;
        float v;
        if (layer == 0)      v = b_ih0[g] + b_hh0[g];
        else if (layer == 1) v = b_ih1[g] + b_hh1[g];
        else                 v = b_ih2[g] + b_hh2[g];
        ((float*)wsu)[gid] = v;
    }
}

// ---------------------------------------------------------------------------
// kT: dt tables (48 x 96): [tmx(+bmx) | tmt(+bmt) | tat(+bat)]
// ---------------------------------------------------------------------------
__global__ void __launch_bounds__(256)
kT(const float* __restrict__ t_emb,
   const float* __restrict__ wmx, const float* __restrict__ wmt,
   const float* __restrict__ wat,
   const float* __restrict__ bmx, const float* __restrict__ bmt,
   const float* __restrict__ bat, float* __restrict__ ttab)
{
    int gid = blockIdx.x * 256 + threadIdx.x;
    if (gid >= 48 * 96) return;
    int dt = gid / 96, o96 = gid % 96;
    const float* te = t_emb + dt * TE;
    int o = o96 & 31;
    float acc;
    const float* w;
    if (o96 < 32)      { acc = bmx[o]; w = wmx + o * MKD + XE; }
    else if (o96 < 64) { acc = bmt[o]; w = wmt + o * MKD + XE; }
    else               { acc = bat[o]; w = wat + o * 64 + TE; }
    for (int d = 0; d < TE; ++d) acc = fmaf(te[d], w[d], acc);
    ttab[dt * 96 + o96] = acc;
}

// ---------------------------------------------------------------------------
// kE: per-edge tables (50000 x 96): [emx | emt | eat]  (no biases)
// ---------------------------------------------------------------------------
__global__ void __launch_bounds__(256)
kE(const float* __restrict__ x_emb, const float* __restrict__ eprop,
   const float* __restrict__ tcost,
   const u32* __restrict__ wmxp, const u32* __restrict__ wmtp,
   const u32* __restrict__ watp0, float* __restrict__ etab)
{
    __shared__ uint4 smx[544], smt[544], sat[128];
    int tid = threadIdx.x;
    for (int i = tid; i < 544; i += 256) {
        smx[i] = ((const uint4*)wmxp)[i];
        smt[i] = ((const uint4*)wmtp)[i];
    }
    if (tid < 128) sat[tid] = ((const uint4*)watp0)[tid];
    __syncthreads();
    int e = blockIdx.x * 256 + tid;
    if (e >= NE) return;

    u32 in[68], tin[16];
    const float* xr = x_emb + (size_t)e * XE;
#pragma unroll
    for (int c = 0; c < 64; ++c) in[c] = packh(xr[2 * c], xr[2 * c + 1]);
    const float* er = eprop + (size_t)e * EP;
#pragma unroll
    for (int c = 0; c < 4; ++c) in[64 + c] = packh(er[2 * c], er[2 * c + 1]);
    const float* tr = tcost + (size_t)e * TE;
#pragma unroll
    for (int c = 0; c < 16; ++c) tin[c] = packh(tr[2 * c], tr[2 * c + 1]);

    float* outp = etab + (size_t)e * 96;
    for (int o = 0; o < OD; ++o) {
        float ax = 0.f, am = 0.f, aa = 0.f;
#pragma unroll
        for (int c4 = 0; c4 < 17; ++c4) {
            uint4 wx = smx[o * 17 + c4], wt = smt[o * 17 + c4];
            ax = dot2f(wx.x, in[c4 * 4 + 0], ax);
            ax = dot2f(wx.y, in[c4 * 4 + 1], ax);
            ax = dot2f(wx.z, in[c4 * 4 + 2], ax);
            ax = dot2f(wx.w, in[c4 * 4 + 3], ax);
            am = dot2f(wt.x, in[c4 * 4 + 0], am);
            am = dot2f(wt.y, in[c4 * 4 + 1], am);
            am = dot2f(wt.z, in[c4 * 4 + 2], am);
            am = dot2f(wt.w, in[c4 * 4 + 3], am);
        }
#pragma unroll
        for (int c4 = 0; c4 < 4; ++c4) {
            uint4 wa = sat[o * 4 + c4];
            aa = dot2f(wa.x, tin[c4 * 4 + 0], aa);
            aa = dot2f(wa.y, tin[c4 * 4 + 1], aa);
            aa = dot2f(wa.z, tin[c4 * 4 + 2], aa);
            aa = dot2f(wa.w, tin[c4 * 4 + 3], aa);
        }
        outp[o] = ax; outp[32 + o] = am; outp[64 + o] = aa;
    }
}

// ---------------------------------------------------------------------------
// kAP: build layer-0 A panel [65536][96 u32] = packed f16 rows of
// [z(16) | x_emb(128) | t_emb(32) | eprop(8) | pad(8)]  (K=192)
// ---------------------------------------------------------------------------
__global__ void __launch_bounds__(512)
kAP(const int* __restrict__ x, const int* __restrict__ dpt,
    const float* __restrict__ z, const float* __restrict__ eprop,
    const float* __restrict__ x_emb, const float* __restrict__ t_emb,
    u32* __restrict__ A0)
{
    int tid = threadIdx.x;
    int i = tid >> 2, q = tid & 3;
    int bl = blockIdx.x * 128 + i;
    int xt = x[bl], dt = dpt[bl];
    int b = bl >> 7, l = bl & 127;
    const float* zr = z + ((size_t)l * B_ + b) * ZD;
    const float* xr = x_emb + (size_t)xt * XE;
    const float* tr = t_emb + (size_t)dt * TE;
    const float* er = eprop + (size_t)xt * EP;
    u32* outp = A0 + (size_t)bl * 96;
#pragma unroll
    for (int cc = 0; cc < 24; ++cc) {
        int c = q * 24 + cc;
        float lo, hi;
        if (c < 8)       { lo = zr[2 * c];          hi = zr[2 * c + 1]; }
        else if (c < 72) { lo = xr[2 * (c - 8)];    hi = xr[2 * (c - 8) + 1]; }
        else if (c < 88) { lo = tr[2 * (c - 72)];   hi = tr[2 * (c - 72) + 1]; }
        else if (c < 92) { lo = er[2 * (c - 88)];   hi = er[2 * (c - 88) + 1]; }
        else             { lo = 0.f;                hi = 0.f; }
        outp[c] = packh(lo, hi);
    }
}

// ---------------------------------------------------------------------------
// kGm<KC>: MFMA GEMM.  Out[M][512] (f16) = A[M][KC*32] @ W[512][KC*32]^T + bsum.
// Block: 512 threads (8 waves), 64 items.  Wave w covers gates w*16 + pass*128.
// A-frags in registers (4 item-tiles x KC chunks); B reused across tiles.
// mfma_f32_16x16x32_f16: A row=lane&15,k=(lane>>4)*8+e; B col=lane&15 same k;
// D col=lane&15, row=(lane>>4)*4+reg.
// ---------------------------------------------------------------------------
template<int KC>
__global__ void __launch_bounds__(512, 2)
kGm(const _Float16* __restrict__ A, const u32* __restrict__ Wp,
    const float* __restrict__ bsum, _Float16* __restrict__ Out)
{
    const int K = KC * 32;
    int tid = threadIdx.x;
    int w = tid >> 6, l = tid & 63;
    int lr = l & 15, lq = l >> 4;
    int bl0 = blockIdx.x * 64;

    half8 a[4][KC];
#pragma unroll
    for (int t = 0; t < 4; ++t)
#pragma unroll
        for (int c = 0; c < KC; ++c)
            a[t][c] = *reinterpret_cast<const half8*>(
                A + (size_t)(bl0 + t * 16 + lr) * K + c * 32 + lq * 8);

#pragma unroll
    for (int pass = 0; pass < 4; ++pass) {
        int g = pass * 128 + w * 16 + lr;
        half8 bfr[KC];
#pragma unroll
        for (int c = 0; c < KC; ++c)
            bfr[c] = *reinterpret_cast<const half8*>(
                (const _Float16*)Wp + (size_t)g * K + c * 32 + lq * 8);
        float bias = bsum[g];
#pragma unroll
        for (int t = 0; t < 4; ++t) {
            f32x4 acc = {0.f, 0.f, 0.f, 0.f};
#pragma unroll
            for (int c = 0; c < KC; ++c)
                acc = __builtin_amdgcn_mfma_f32_16x16x32_f16(a[t][c], bfr[c], acc, 0, 0, 0);
#pragma unroll
            for (int j = 0; j < 4; ++j) {
                int item = bl0 + t * 16 + lq * 4 + j;
                Out[(size_t)item * G4 + g] = (_Float16)(acc[j] + bias);
            }
        }
    }
}

// ---------------------------------------------------------------------------
// kLrec: serial LSTM recurrence, one layer.  512 blocks x 256 threads,
// 1 batch row per block, 2 gates per thread (p, p+256); w_hh rows in regs.
// gin = precomputed input-gates (+bias), f16 [b*L+l][512].
// ---------------------------------------------------------------------------
__global__ void __launch_bounds__(256, 2)
kLrec(const _Float16* __restrict__ gin, const u32* __restrict__ whp,
      _Float16* __restrict__ hout)
{
    __shared__ u32 sh[64];        // packed f16 h[128]
    __shared__ float sg[G4];
    int t = threadIdx.x;          // 0..255
    int bidx = blockIdx.x;        // batch row

    uint4 wA[16], wB[16];
#pragma unroll
    for (int j4 = 0; j4 < 16; ++j4) {
        wA[j4] = ((const uint4*)whp)[t * 16 + j4];
        wB[j4] = ((const uint4*)whp)[(t + 256) * 16 + j4];
    }
    if (t < 64) sh[t] = 0;
    float c_reg = 0.f;
    const _Float16* gbase = gin + (size_t)bidx * L_ * G4;
    float gA = (float)gbase[t], gB = (float)gbase[t + 256];
    __syncthreads();

    for (int l = 0; l < L_; ++l) {
        const _Float16* gnext = gbase + (size_t)(l < L_ - 1 ? l + 1 : l) * G4;
        float nA = (float)gnext[t], nB = (float)gnext[t + 256];
        float aA = gA, aB = gB;
        const uint4* shv = (const uint4*)sh;
#pragma unroll
        for (int j4 = 0; j4 < 16; ++j4) {
            uint4 hv = shv[j4];
            aA = dot4(wA[j4], hv, aA);
            aB = dot4(wB[j4], hv, aB);
        }
        sg[t] = aA; sg[t + 256] = aB;
        __syncthreads();
        if (t < 128) {
            float gi = sg[t], gf = sg[H_ + t], gg = sg[2 * H_ + t], go = sg[3 * H_ + t];
            float c = sigm(gf) * c_reg + sigm(gi) * tanh_f(gg);
            float h = sigm(go) * tanh_f(c);
            c_reg = c;
            _Float16 hh = (_Float16)h;
            ((_Float16*)sh)[t] = hh;
            hout[((size_t)bidx * L_ + l) * H_ + t] = hh;
        }
        __syncthreads();
        gA = nA; gB = nB;
    }
}

// ---------------------------------------------------------------------------
// kX2: fused epilogue.  afterx from h2 (f16 dot2), px/pt from etab+ttab.
// ---------------------------------------------------------------------------
__global__ void __launch_bounds__(256)
kX2(const int* __restrict__ x, const int* __restrict__ dpt,
    const int* __restrict__ adj, const __half* __restrict__ h2seq,
    const u32* __restrict__ wap, const float* __restrict__ bax,
    const float* __restrict__ etab, const float* __restrict__ ttab,
    float* __restrict__ pred_x, float* __restrict__ pred_t)
{
    __shared__ uint4 swp[512];
    __shared__ float stt[48 * 96];
    __shared__ float sbax[32];
    int tid = threadIdx.x;
    for (int i = tid; i < 512; i += 256) swp[i] = ((const uint4*)wap)[i];
    for (int i = tid; i < 4608; i += 256) stt[i] = ttab[i];
    if (tid < 32) sbax[tid] = bax[tid];
    __syncthreads();

    int bl = blockIdx.x * 256 + tid;
    int xt = x[bl], dt = dpt[bl];

    uint4 h2r[16];
    const uint4* h2p = (const uint4*)(h2seq + (size_t)bl * H_);
#pragma unroll
    for (int q = 0; q < 16; ++q) h2r[q] = h2p[q];

    float afterx[OD];
    for (int o = 0; o < OD; ++o) {
        float acc = sbax[o];
#pragma unroll
        for (int q = 0; q < 16; ++q) {
            uint4 w = swp[o * 16 + q];
            acc = dot2f(w.x, h2r[q].x, acc);
            acc = dot2f(w.y, h2r[q].y, acc);
            acc = dot2f(w.z, h2r[q].z, acc);
            acc = dot2f(w.w, h2r[q].w, acc);
        }
        afterx[o] = acc > 0.f ? acc : 0.f;
    }

    const float4* tp = (const float4*)(stt + dt * 96);
    float px[K_];
#pragma unroll
    for (int k = 0; k < K_; ++k) {
        int a = adj[xt * K_ + k];
        int ac = a < NE ? a : 0;
        const float4* ep = (const float4*)(etab + (size_t)ac * 96);
        float sx = 0.f, st = 0.f;
#pragma unroll
        for (int q = 0; q < 8; ++q) {
            float4 e = ep[q], tt = tp[q];
            sx += afterx[q * 4 + 0] * (e.x + tt.x)
                + afterx[q * 4 + 1] * (e.y + tt.y)
                + afterx[q * 4 + 2] * (e.z + tt.z)
                + afterx[q * 4 + 3] * (e.w + tt.w);
        }
#pragma unroll
        for (int q = 0; q < 8; ++q) {
            float4 em = ep[8 + q], tm = tp[8 + q];
            float4 ea = ep[16 + q], ta = tp[16 + q];
            float at0 = fmaxf(ea.x + ta.x, 0.f);
            float at1 = fmaxf(ea.y + ta.y, 0.f);
            float at2 = fmaxf(ea.z + ta.z, 0.f);
            float at3 = fmaxf(ea.w + ta.w, 0.f);
            st += at0 * (em.x + tm.x) + at1 * (em.y + tm.y)
                + at2 * (em.z + tm.z) + at3 * (em.w + tm.w);
        }
        px[k] = (a == NE) ? -INFINITY : sx;
        pred_t[(size_t)bl * K_ + k] = 1.f / (1.f + expf(-st));
    }

    float m = px[0];
#pragma unroll
    for (int k = 1; k < K_; ++k) m = fmaxf(m, px[k]);
    float ssum = 0.f;
#pragma unroll
    for (int k = 0; k < K_; ++k) ssum += expf(px[k] - m);
    float lse = logf(ssum) + m;
#pragma unroll
    for (int k = 0; k < K_; ++k)
        pred_x[(size_t)bl * K_ + k] = px[k] - lse;
}

// ---------------------------------------------------------------------------
extern "C" void kernel_launch(void* const* d_in, const int* in_sizes, int n_in,
                              void* d_out, int out_size, void* d_ws, size_t ws_size,
                              hipStream_t stream)
{
    (void)in_sizes; (void)n_in; (void)out_size; (void)ws_size;

    const int*   x      = (const int*)  d_in[0];
    const int*   dpt    = (const int*)  d_in[1];
    const float* z      = (const float*)d_in[2];
    const int*   adj    = (const int*)  d_in[3];
    const float* eprop  = (const float*)d_in[4];
    const float* x_emb  = (const float*)d_in[5];
    const float* t_emb  = (const float*)d_in[6];
    const float* tcost  = (const float*)d_in[7];
    const float* w_ih0  = (const float*)d_in[8];
    const float* w_hh0  = (const float*)d_in[9];
    const float* b_ih0  = (const float*)d_in[10];
    const float* b_hh0  = (const float*)d_in[11];
    const float* w_ih1  = (const float*)d_in[12];
    const float* w_hh1  = (const float*)d_in[13];
    const float* b_ih1  = (const float*)d_in[14];
    const float* b_hh1  = (const float*)d_in[15];
    const float* w_ih2  = (const float*)d_in[16];
    const float* w_hh2  = (const float*)d_in[17];
    const float* b_ih2  = (const float*)d_in[18];
    const float* b_hh2  = (const float*)d_in[19];
    const float* wax    = (const float*)d_in[20];
    const float* bax    = (const float*)d_in[21];
    const float* wat    = (const float*)d_in[22];
    const float* bat    = (const float*)d_in[23];
    const float* wmx    = (const float*)d_in[24];
    const float* bmx    = (const float*)d_in[25];
    const float* wmt    = (const float*)d_in[26];
    const float* bmt    = (const float*)d_in[27];

    float* out    = (float*)d_out;
    float* pred_x = out;
    float* pred_t = out + (size_t)B_ * L_ * K_;

    u32* wsu = (u32*)d_ws;
    u32* wih0p = wsu;                 // 49152
    u32* whp0  = wsu + 49152;
    u32* wih1p = wsu + 81920;
    u32* whp1  = wsu + 114688;
    u32* wih2p = wsu + 147456;
    u32* whp2  = wsu + 180224;
    u32* wap   = wsu + 212992;
    u32* wmxp  = wsu + 215040;
    u32* wmtp  = wsu + 217216;
    u32* watp0 = wsu + 219392;
    float* bsum = (float*)(wsu + 219904);          // [3][512]
    u32* A0    = wsu + 221440;                      // 65536*96
    _Float16* gin   = (_Float16*)(wsu + 6512896);   // 65536*512 f16
    _Float16* h0seq = (_Float16*)(wsu + 23290112);  // 65536*128 f16
    _Float16* h1seq = (_Float16*)(wsu + 27484416);
    _Float16* h2seq = (_Float16*)(wsu + 31678720);
    float* etab = (float*)(wsu + 35873024);         // 50000*96
    float* ttab = (float*)(wsu + 40673024);         // 4608

    kW2<<<865, 256, 0, stream>>>(w_ih0, w_hh0, w_ih1, w_hh1, w_ih2, w_hh2,
                                 wax, wmx, wmt, wat,
                                 b_ih0, b_hh0, b_ih1, b_hh1, b_ih2, b_hh2, wsu);

    kT<<<18, 256, 0, stream>>>(t_emb, wmx, wmt, wat, bmx, bmt, bat, ttab);

    kE<<<196, 256, 0, stream>>>(x_emb, eprop, tcost, wmxp, wmtp, watp0, etab);

    kAP<<<512, 512, 0, stream>>>(x, dpt, z, eprop, x_emb, t_emb, A0);

    kGm<6><<<1024, 512, 0, stream>>>((const _Float16*)A0, wih0p, bsum + 0, gin);
    kLrec<<<512, 256, 0, stream>>>(gin, whp0, h0seq);

    kGm<4><<<1024, 512, 0, stream>>>(h0seq, wih1p, bsum + 512, gin);
    kLrec<<<512, 256, 0, stream>>>(gin, whp1, h1seq);

    kGm<4><<<1024, 512, 0, stream>>>(h1seq, wih2p, bsum + 1024, gin);
    kLrec<<<512, 256, 0, stream>>>(gin, whp2, h2seq);

    kX2<<<256, 256, 0, stream>>>(x, dpt, adj, (const __half*)h2seq, wap, bax,
                                 etab, ttab, pred_x, pred_t);
}